// Round 5
// baseline (1314.278 us; speedup 1.0000x reference)
//
#include <hip/hip_runtime.h>

#define TT 100
#define HH 100
#define NL 5
#define NOUT 10
#define NG 400        // 4*H gate rows
#define CC 10         // timesteps per inter-layer handoff chunk
#define NC (TT / CC)  // chunks

typedef float v2f __attribute__((ext_vector_type(2)));
typedef _Float16 h2f __attribute__((ext_vector_type(2)));

// dynamic LDS layout (bytes)
#define WL_OFF  0        // uint4[13*400]  f16 Whh, [kchunk][lane-row][8 f16] = 83200
#define XCH_OFF 83200    // float[1000]    x chunk                            = 4000
#define OCH_OFF 87200    // float[1000]    output chunk                       = 4000
#define HBF_OFF 91200    // ushort[2*104]  h as f16, double-buffered (pad 0)  = 416
#define SMEM_BYTES 91616

__device__ __forceinline__ float sigm(float x) { return 1.f / (1.f + __expf(-x)); }

__device__ __forceinline__ float fdot2u(unsigned int a, unsigned int b, float c) {
#if __has_builtin(__builtin_amdgcn_fdot2)
  return __builtin_amdgcn_fdot2(__builtin_bit_cast(h2f, a),
                                __builtin_bit_cast(h2f, b), c, false);
#else
  float d;
  asm("v_dot2_f32_f16 %0, %1, %2, %3" : "=v"(d) : "v"(a), "v"(b), "v"(c));
  return d;
#endif
}

// One block per layer. Lane tid<400: j=tid>>2 (element), g=tid&3 (gate),
// weight row = g*100+j. Whh lives in LDS as f16 (allocator-proof, unlike
// VGPRs: R2-R4 all spilled). Wih@x precomputed per chunk into 10 NAMED
// scalar registers (same-thread producer/consumer).
__launch_bounds__(512, 1)
__global__ void lstm_pipe_kernel(
    const float* __restrict__ input,   // [T, H]
    const float* __restrict__ Wih,     // [L, 4H, H]
    const float* __restrict__ Whh,     // [L, 4H, H]
    const float* __restrict__ bih,     // [L, 4H]
    const float* __restrict__ bhh,     // [L, 4H]
    const float* __restrict__ Wout,    // [OUT, H]
    const float* __restrict__ bout,    // [OUT]
    float* __restrict__ out,           // [T, OUT]
    int* __restrict__ flags,           // [L-1, NC] chunk-ready flags
    float* __restrict__ xstage)        // [L-1, T, H] inter-layer activations
{
  extern __shared__ __align__(16) char smem[];
  uint4* wl4 = (uint4*)(smem + WL_OFF);
  float* xch = (float*)(smem + XCH_OFF);
  float* och = (float*)(smem + OCH_OFF);
  unsigned short* hbs = (unsigned short*)(smem + HBF_OFF);

  const int l = blockIdx.x;
  const int tid = threadIdx.x;
  const int j = tid >> 2;
  const int g = tid & 3;
  const bool act = (tid < NG);
  const int rowc = act ? (g * HH + j) : 0;  // weight-matrix row, clamped

  // ---- one-time: Whh row -> LDS as f16, [m][lane][8] ----
  if (act) {
    const float* wr = Whh + (size_t)l * NG * HH + (size_t)rowc * HH;
#pragma unroll
    for (int m = 0; m < 13; ++m) {
      float f[8];
#pragma unroll
      for (int k2 = 0; k2 < 8; ++k2) {
        int k = m * 8 + k2;
        f[k2] = (k < HH) ? wr[k] : 0.f;
      }
      uint4 u;
      unsigned int up[4];
#pragma unroll
      for (int p = 0; p < 4; ++p) {
        _Float16 lo = (_Float16)f[2 * p], hi = (_Float16)f[2 * p + 1];
        up[p] = (unsigned int)__builtin_bit_cast(unsigned short, lo) |
                ((unsigned int)__builtin_bit_cast(unsigned short, hi) << 16);
      }
      u.x = up[0]; u.y = up[1]; u.z = up[2]; u.w = up[3];
      wl4[m * NG + tid] = u;
    }
  }
  if (tid < 104) { hbs[tid] = 0; hbs[104 + tid] = 0; }  // h0=0 + k-pad zeros

  const float* wihr = Wih + (size_t)l * NG * HH + (size_t)rowc * HH;
  const float bias = bih[l * NG + rowc] + bhh[l * NG + rowc];
  float c = 0.f;
  __syncthreads();

  for (int ch = 0; ch < NC; ++ch) {
    // ---- acquire + load x chunk into LDS ----
    if (l == 0) {
      if (tid < CC * HH / 4)
        ((float4*)xch)[tid] = ((const float4*)(input + ch * CC * HH))[tid];
    } else {
      if (tid == 0) {
        const int* fl = flags + (l - 1) * NC + ch;
        while (__hip_atomic_load(fl, __ATOMIC_ACQUIRE, __HIP_MEMORY_SCOPE_AGENT) == 0)
          __builtin_amdgcn_s_sleep(1);
      }
      __syncthreads();
      const float4* src =
          (const float4*)(xstage + ((size_t)(l - 1) * TT + (size_t)ch * CC) * HH);
      if (tid < CC * HH / 4) ((float4*)xch)[tid] = src[tid];
    }
    __syncthreads();  // xch ready for preamble

    // ---- preamble: XGs = bias + Wih[row].x_s, all in named registers ----
    v2f A0={0,0},A1={0,0},A2={0,0},A3={0,0},A4={0,0},A5={0,0},A6={0,0},A7={0,0},A8={0,0},A9={0,0};
    {
      const float4* wp = (const float4*)wihr;  // L2-resident after chunk 0
#define PRE(kb, s)                                                        \
  {                                                                       \
    const float4* xp = (const float4*)(xch + (s)*HH + (kb)*20);           \
    float4 x0 = xp[0], x1 = xp[1], x2 = xp[2], x3 = xp[3], x4 = xp[4];    \
    A##s += (v2f){w0.x, w0.y} * (v2f){x0.x, x0.y};                        \
    A##s += (v2f){w0.z, w0.w} * (v2f){x0.z, x0.w};                        \
    A##s += (v2f){w1.x, w1.y} * (v2f){x1.x, x1.y};                        \
    A##s += (v2f){w1.z, w1.w} * (v2f){x1.z, x1.w};                        \
    A##s += (v2f){w2.x, w2.y} * (v2f){x2.x, x2.y};                        \
    A##s += (v2f){w2.z, w2.w} * (v2f){x2.z, x2.w};                        \
    A##s += (v2f){w3.x, w3.y} * (v2f){x3.x, x3.y};                        \
    A##s += (v2f){w3.z, w3.w} * (v2f){x3.z, x3.w};                        \
    A##s += (v2f){w4.x, w4.y} * (v2f){x4.x, x4.y};                        \
    A##s += (v2f){w4.z, w4.w} * (v2f){x4.z, x4.w};                        \
  }
#define KBLK(kb)                                                          \
  {                                                                       \
    float4 w0 = wp[(kb)*5 + 0], w1 = wp[(kb)*5 + 1], w2 = wp[(kb)*5 + 2], \
           w3 = wp[(kb)*5 + 3], w4 = wp[(kb)*5 + 4];                      \
    PRE(kb, 0) PRE(kb, 1) PRE(kb, 2) PRE(kb, 3) PRE(kb, 4)                \
    PRE(kb, 5) PRE(kb, 6) PRE(kb, 7) PRE(kb, 8) PRE(kb, 9)                \
  }
      KBLK(0) KBLK(1) KBLK(2) KBLK(3) KBLK(4)
    }
    float XG0 = bias + A0.x + A0.y, XG1 = bias + A1.x + A1.y;
    float XG2 = bias + A2.x + A2.y, XG3 = bias + A3.x + A3.y;
    float XG4 = bias + A4.x + A4.y, XG5 = bias + A5.x + A5.y;
    float XG6 = bias + A6.x + A6.y, XG7 = bias + A7.x + A7.y;
    float XG8 = bias + A8.x + A8.y, XG9 = bias + A9.x + A9.y;

    // ---- CC recurrent steps, one barrier each ----
#define DOTM(m)                                      \
  {                                                  \
    uint4 hv = hb[m];                                \
    uint4 wv = wl4[(m)*NG + tid];                    \
    a0 = fdot2u(wv.x, hv.x, a0);                     \
    a1 = fdot2u(wv.y, hv.y, a1);                     \
    a2 = fdot2u(wv.z, hv.z, a2);                     \
    a3 = fdot2u(wv.w, hv.w, a3);                     \
  }
#define STEP(s, XGS)                                                    \
  {                                                                     \
    __syncthreads(); /* hbf[s&1] ready (and xch/XG at s==0) */          \
    const uint4* hb = (const uint4*)(hbs + ((s)&1) * 104);              \
    float a0 = 0.f, a1 = 0.f, a2 = 0.f, a3 = 0.f;                       \
    DOTM(0) DOTM(1) DOTM(2) DOTM(3) DOTM(4) DOTM(5) DOTM(6)             \
    DOTM(7) DOTM(8) DOTM(9) DOTM(10) DOTM(11) DOTM(12)                  \
    float aa = ((a0 + a1) + (a2 + a3)) + XGS;                           \
    bool isg = (g == 2);                                                \
    float mm = isg ? 2.f : 1.f;                                         \
    float sg = 1.f / (1.f + __expf(-mm * aa));                          \
    float vv = isg ? 2.f * sg - 1.f : sg;                               \
    float v1 = __shfl_xor(vv, 1);                                       \
    float v2v = __shfl_xor(vv, 2);                                      \
    float v3 = __shfl_xor(v1, 2);                                       \
    if (g == 0 && j < HH) {                                             \
      c = v1 * c + vv * v2v;                                            \
      float tc = 2.f / (1.f + __expf(-2.f * c)) - 1.f;                  \
      float h = v3 * tc;                                                \
      och[(s)*HH + j] = (l < NL - 1) ? fmaxf(h, 0.f) : h;               \
      _Float16 hf = (_Float16)h;                                        \
      hbs[(((s) + 1) & 1) * 104 + j] =                                  \
          __builtin_bit_cast(unsigned short, hf);                       \
    }                                                                   \
  }
    STEP(0, XG0) STEP(1, XG1) STEP(2, XG2) STEP(3, XG3) STEP(4, XG4)
    STEP(5, XG5) STEP(6, XG6) STEP(7, XG7) STEP(8, XG8) STEP(9, XG9)

    __syncthreads();  // och complete

    if (l < NL - 1) {
      // ---- publish chunk: coalesced write + fence + flag ----
      float4* dst = (float4*)(xstage + ((size_t)l * TT + (size_t)ch * CC) * HH);
      if (tid < CC * HH / 4) dst[tid] = ((const float4*)och)[tid];
      __syncthreads();  // all waves' global stores drained
      if (tid == 0) {
        __threadfence();
        __hip_atomic_store(flags + l * NC + ch, 1, __ATOMIC_RELEASE,
                           __HIP_MEMORY_SCOPE_AGENT);
      }
    } else {
      // ---- batched output projection for the whole chunk ----
      if (tid < NG) {
        int p = tid >> 2, q = tid & 3;
        int s2 = p / 10, r = p % 10;
        const float* wrow = Wout + r * HH + q * 25;
        const float* hrow = och + s2 * HH + q * 25;
        float acc = 0.f;
#pragma unroll
        for (int m2 = 0; m2 < 25; ++m2) acc = fmaf(wrow[m2], hrow[m2], acc);
        acc += __shfl_xor(acc, 1);
        acc += __shfl_xor(acc, 2);
        if (q == 0) out[(ch * CC + s2) * NOUT + r] = sigm(acc + bout[r]);
      }
    }
  }
}

extern "C" void kernel_launch(void* const* d_in, const int* in_sizes, int n_in,
                              void* d_out, int out_size, void* d_ws, size_t ws_size,
                              hipStream_t stream) {
  const float* input = (const float*)d_in[0];
  const float* Wih   = (const float*)d_in[1];
  const float* Whh   = (const float*)d_in[2];
  const float* bih   = (const float*)d_in[3];
  const float* bhh   = (const float*)d_in[4];
  const float* Wout  = (const float*)d_in[5];
  const float* bout  = (const float*)d_in[6];
  float* out = (float*)d_out;

  // workspace: [0,2048) flags ((L-1)*NC = 40 ints used),
  //            [2048, 2048+160000) xstage (4*100*100 floats)
  int* flags = (int*)d_ws;
  float* xstage = (float*)((char*)d_ws + 2048);

  // allow >64KB dynamic LDS (host-side, idempotent, graph-capture-safe)
  (void)hipFuncSetAttribute((const void*)lstm_pipe_kernel,
                            hipFuncAttributeMaxDynamicSharedMemorySize,
                            SMEM_BYTES);

  // flags must be zero at kernel start on EVERY call (graph replays included)
  hipMemsetAsync(d_ws, 0, 2048, stream);

  lstm_pipe_kernel<<<dim3(NL), dim3(512), SMEM_BYTES, stream>>>(
      input, Wih, Whh, bih, bhh, Wout, bout, out, flags, xstage);
}

// Round 6
// 296.507 us; speedup vs baseline: 4.4325x; 4.4325x over previous
//
#include <hip/hip_runtime.h>

#define TT 100
#define HH 100
#define NL 5
#define NOUT 10
#define NG 400        // 4*H gate rows
#define CC 10         // timesteps per inter-layer handoff chunk
#define NC (TT / CC)  // chunks
#define KC 13         // k-chunks of 8 halves (104 halves, last 4 zero-pad)
#define KH 104        // padded k length in halves

typedef _Float16 h2f __attribute__((ext_vector_type(2)));

__device__ __forceinline__ float sigm(float x) { return 1.f / (1.f + __expf(-x)); }

__device__ __forceinline__ float fdot2u(unsigned a, unsigned b, float c) {
#if __has_builtin(__builtin_amdgcn_fdot2)
  return __builtin_amdgcn_fdot2(__builtin_bit_cast(h2f, a),
                                __builtin_bit_cast(h2f, b), c, false);
#else
  float d;
  asm("v_dot2_f32_f16 %0, %1, %2, %3" : "=v"(d) : "v"(a), "v"(b), "v"(c));
  return d;
#endif
}

__device__ __forceinline__ unsigned pk16(float lo, float hi) {
  _Float16 l = (_Float16)lo, h = (_Float16)hi;
  return (unsigned)__builtin_bit_cast(unsigned short, l) |
         ((unsigned)__builtin_bit_cast(unsigned short, h) << 16);
}

// ---- init: pack Wih/Whh to f16, layout [l*13+m][lane] of uint4 (8 halves) ----
// lane tid owns weight row (tid&3)*100 + (tid>>2); a wave's 64 lanes then read
// 64 consecutive uint4 = 1KB contiguous per load instruction in the main loop.
__global__ void pack_w(const float* __restrict__ Wih, const float* __restrict__ Whh,
                       uint4* __restrict__ wil, uint4* __restrict__ whl) {
  const int b = blockIdx.x;  // 0..64 = l*13 + m
  const int l = b / KC, m = b % KC;
  const int tid = threadIdx.x;
  if (tid >= NG) return;
  const int row = (tid & 3) * HH + (tid >> 2);
  const float* sh = Whh + ((size_t)l * NG + row) * HH;
  const float* si = Wih + ((size_t)l * NG + row) * HH;
  float4 ha, hb4, ia, ib;
  if (m < 12) {
    ha = *(const float4*)(sh + 8 * m); hb4 = *(const float4*)(sh + 8 * m + 4);
    ia = *(const float4*)(si + 8 * m); ib = *(const float4*)(si + 8 * m + 4);
  } else {  // k = 96..103 : 4 valid + 4 zero-pad
    ha = *(const float4*)(sh + 96); hb4 = make_float4(0.f, 0.f, 0.f, 0.f);
    ia = *(const float4*)(si + 96); ib = make_float4(0.f, 0.f, 0.f, 0.f);
  }
  uint4 uh, ui;
  uh.x = pk16(ha.x, ha.y); uh.y = pk16(ha.z, ha.w);
  uh.z = pk16(hb4.x, hb4.y); uh.w = pk16(hb4.z, hb4.w);
  ui.x = pk16(ia.x, ia.y); ui.y = pk16(ia.z, ia.w);
  ui.z = pk16(ib.x, ib.y); ui.w = pk16(ib.z, ib.w);
  whl[(size_t)b * NG + tid] = uh;
  wil[(size_t)b * NG + tid] = ui;
}

// ---- main: one block per layer, R4 skeleton, f16 weight streams from L2 ----
__launch_bounds__(512, 2)
__global__ void lstm_pipe_kernel(
    const float* __restrict__ input,   // [T, H] fp32
    const float* __restrict__ bih,     // [L, 4H]
    const float* __restrict__ bhh,     // [L, 4H]
    const float* __restrict__ Wout,    // [OUT, H]
    const float* __restrict__ bout,    // [OUT]
    float* __restrict__ out,           // [T, OUT]
    int* __restrict__ flags,           // [L-1, NC]
    unsigned short* __restrict__ xst,  // [L-1, T, KH] f16 inter-layer acts
    const uint4* __restrict__ whl,     // packed f16 Whh
    const uint4* __restrict__ wil)     // packed f16 Wih
{
  __shared__ __align__(16) unsigned short xh[CC * KH];     // x chunk, f16
  __shared__ __align__(16) unsigned short hb[2 * KH];      // h double-buffered, f16
  __shared__ __align__(16) unsigned short och16[CC * KH];  // publish chunk, f16
  __shared__ __align__(16) float ochf[CC * HH];            // layer-4 h, fp32

  const int l = blockIdx.x;
  const int tid = threadIdx.x;
  const int j = tid >> 2;
  const int g = tid & 3;
  const bool act = (tid < NG);
  const int row = act ? (g * HH + j) : 0;

  const uint4* wh0 = whl + (size_t)l * KC * NG + tid;  // index m*NG
  const uint4* wi0 = wil + (size_t)l * KC * NG + tid;
  const float bias = bih[l * NG + row] + bhh[l * NG + row];

  // one-time zero: h0 and all k-pads (never overwritten afterwards)
  if (tid < KH) { hb[tid] = 0; hb[KH + tid] = 0; }
  if (tid < CC) {
    *(uint2*)(xh + tid * KH + HH) = make_uint2(0u, 0u);
    *(uint2*)(och16 + tid * KH + HH) = make_uint2(0u, 0u);
  }
  float c = 0.f;

  for (int ch = 0; ch < NC; ++ch) {
    // ---- acquire x chunk into LDS (f16) ----
    if (l == 0) {
      if (tid < 250) {  // 250 float4 = 1000 fp32 inputs -> f16 pairs
        float4 v = ((const float4*)(input + ch * CC * HH))[tid];
        int s = tid / 25, q = tid % 25;
        *(uint2*)(xh + s * KH + q * 4) = make_uint2(pk16(v.x, v.y), pk16(v.z, v.w));
      }
    } else {
      if (tid == 0) {
        const int* fl = flags + (l - 1) * NC + ch;
        while (__hip_atomic_load(fl, __ATOMIC_ACQUIRE, __HIP_MEMORY_SCOPE_AGENT) == 0)
          __builtin_amdgcn_s_sleep(1);
      }
      __syncthreads();
      const uint4* src =
          (const uint4*)(xst + ((size_t)(l - 1) * TT + (size_t)ch * CC) * KH);
      if (tid < 130) ((uint4*)xh)[tid] = src[tid];  // 130 uint4 = 2080B chunk
    }

    // ---- CC recurrent steps, one barrier each ----
#define DOT(m)                                                       \
  {                                                                  \
    uint4 hv = hb4[m];                                               \
    uint4 xv = xp4[m];                                               \
    uint4 uw = wh0[(m)*NG];                                          \
    uint4 vw = wi0[(m)*NG];                                          \
    a0 = fdot2u(uw.x, hv.x, a0); a1 = fdot2u(uw.y, hv.y, a1);        \
    a2 = fdot2u(uw.z, hv.z, a2); a3 = fdot2u(uw.w, hv.w, a3);        \
    b0 = fdot2u(vw.x, xv.x, b0); b1 = fdot2u(vw.y, xv.y, b1);        \
    b2 = fdot2u(vw.z, xv.z, b2); b3 = fdot2u(vw.w, xv.w, b3);        \
  }
#pragma unroll 2
    for (int s = 0; s < CC; ++s) {
      __syncthreads();  // hb[s&1] ready (and xh at s==0)
      if (act) {
        const uint4* hb4 = (const uint4*)(hb + (s & 1) * KH);
        const uint4* xp4 = (const uint4*)(xh + s * KH);
        float a0 = 0.f, a1 = 0.f, a2 = 0.f, a3 = 0.f;
        float b0 = 0.f, b1 = 0.f, b2 = 0.f, b3 = 0.f;
        DOT(0) DOT(1) DOT(2) DOT(3) DOT(4) DOT(5) DOT(6)
        DOT(7) DOT(8) DOT(9) DOT(10) DOT(11) DOT(12)
        float aa = ((a0 + a1) + (a2 + a3)) + ((b0 + b1) + (b2 + b3)) + bias;

        bool isg = (g == 2);
        float mm = isg ? 2.f : 1.f;
        float sg = 1.f / (1.f + __expf(-mm * aa));
        float vv = isg ? 2.f * sg - 1.f : sg;  // sigmoid, or tanh=2*sigm(2a)-1

        float v1 = __shfl_xor(vv, 1);
        float v2v = __shfl_xor(vv, 2);
        float v3 = __shfl_xor(v1, 2);
        if (g == 0) {  // vv=i, v1=f, v2v=g~, v3=o
          c = v1 * c + vv * v2v;
          float tc = 2.f / (1.f + __expf(-2.f * c)) - 1.f;
          float h = v3 * tc;
          hb[((s + 1) & 1) * KH + j] =
              __builtin_bit_cast(unsigned short, (_Float16)h);
          if (l < NL - 1) {
            och16[s * KH + j] =
                __builtin_bit_cast(unsigned short, (_Float16)fmaxf(h, 0.f));
          } else {
            ochf[s * HH + j] = h;
          }
        }
      }
    }
    __syncthreads();  // last step's och writes visible

    if (l < NL - 1) {
      // ---- publish chunk (f16): coalesced write + fence + flag ----
      uint4* dst = (uint4*)(xst + ((size_t)l * TT + (size_t)ch * CC) * KH);
      if (tid < 130) dst[tid] = ((const uint4*)och16)[tid];
      __syncthreads();  // all waves' global stores drained
      if (tid == 0) {
        __threadfence();
        __hip_atomic_store(flags + l * NC + ch, 1, __ATOMIC_RELEASE,
                           __HIP_MEMORY_SCOPE_AGENT);
      }
    } else {
      // ---- batched output projection for the chunk (fp32) ----
      if (tid < NG) {
        int p = tid >> 2, q = tid & 3;
        int s2 = p / 10, r = p % 10;
        const float* wrow = Wout + r * HH + q * 25;
        const float* hrow = ochf + s2 * HH + q * 25;
        float acc = 0.f;
#pragma unroll
        for (int m2 = 0; m2 < 25; ++m2) acc = fmaf(wrow[m2], hrow[m2], acc);
        acc += __shfl_xor(acc, 1);
        acc += __shfl_xor(acc, 2);
        if (q == 0) out[(ch * CC + s2) * NOUT + r] = sigm(acc + bout[r]);
      }
    }
  }
}

extern "C" void kernel_launch(void* const* d_in, const int* in_sizes, int n_in,
                              void* d_out, int out_size, void* d_ws, size_t ws_size,
                              hipStream_t stream) {
  const float* input = (const float*)d_in[0];
  const float* Wih   = (const float*)d_in[1];
  const float* Whh   = (const float*)d_in[2];
  const float* bih   = (const float*)d_in[3];
  const float* bhh   = (const float*)d_in[4];
  const float* Wout  = (const float*)d_in[5];
  const float* bout  = (const float*)d_in[6];
  float* out = (float*)d_out;

  // ws layout (bytes):
  //   [0, 2048)            flags ((L-1)*NC = 40 ints used)
  //   [2048, 85248)        xst16: (L-1)*T*KH halves = 83200
  //   [85248, 501248)      whl:  5*13*400 uint4 = 416000
  //   [501248, 917248)     wil:  5*13*400 uint4 = 416000
  int* flags = (int*)d_ws;
  unsigned short* xst = (unsigned short*)((char*)d_ws + 2048);
  uint4* whl = (uint4*)((char*)d_ws + 85248);
  uint4* wil = (uint4*)((char*)d_ws + 501248);

  // flags must be zero at kernel start on EVERY call (graph replays included)
  hipMemsetAsync(d_ws, 0, 2048, stream);

  pack_w<<<dim3(NL * KC), dim3(512), 0, stream>>>(Wih, Whh, wil, whl);

  lstm_pipe_kernel<<<dim3(NL), dim3(512), 0, stream>>>(
      input, bih, bhh, Wout, bout, out, flags, xst, whl, wil);
}

// Round 7
// 219.879 us; speedup vs baseline: 5.9773x; 1.3485x over previous
//
#include <hip/hip_runtime.h>

#define TT 100
#define HH 100
#define NL 5
#define NOUT 10
#define NG 400        // 4*H gate rows
#define CC 10         // timesteps per inter-layer handoff chunk
#define NC (TT / CC)  // chunks
#define KC 13         // k-chunks of 8 halves (104 halves, last 4 zero-pad)
#define KH 104        // padded k length in halves

typedef _Float16 h2f __attribute__((ext_vector_type(2)));

// dynamic LDS layout (bytes, all 16B-aligned)
#define WH_OFF   0       // uint4[13*400] f16 Whh  = 83200
#define XH_OFF   83200   // ushort[10*104] x chunk = 2080
#define OCH_OFF  85280   // ushort[10*104] publish = 2080
#define HB_OFF   87360   // ushort[2*104] h dbuf   = 416
#define OCHF_OFF 87776   // float[10*100] L4 h     = 4000
#define SMEM_BYTES 91776

__device__ __forceinline__ float sigm(float x) { return 1.f / (1.f + __expf(-x)); }

__device__ __forceinline__ float fdot2u(unsigned a, unsigned b, float c) {
#if __has_builtin(__builtin_amdgcn_fdot2)
  return __builtin_amdgcn_fdot2(__builtin_bit_cast(h2f, a),
                                __builtin_bit_cast(h2f, b), c, false);
#else
  float d;
  asm("v_dot2_f32_f16 %0, %1, %2, %3" : "=v"(d) : "v"(a), "v"(b), "v"(c));
  return d;
#endif
}

__device__ __forceinline__ unsigned pk16(float lo, float hi) {
  _Float16 l = (_Float16)lo, h = (_Float16)hi;
  return (unsigned)__builtin_bit_cast(unsigned short, l) |
         ((unsigned)__builtin_bit_cast(unsigned short, h) << 16);
}

// ---- init: pack Wih/Whh to f16, layout [l*13+m][lane] of uint4 (8 halves) ----
__global__ void pack_w(const float* __restrict__ Wih, const float* __restrict__ Whh,
                       uint4* __restrict__ wil, uint4* __restrict__ whl) {
  const int b = blockIdx.x;  // l*13 + m
  const int l = b / KC, m = b % KC;
  const int tid = threadIdx.x;
  if (tid >= NG) return;
  const int row = (tid & 3) * HH + (tid >> 2);
  const float* sh = Whh + ((size_t)l * NG + row) * HH;
  const float* si = Wih + ((size_t)l * NG + row) * HH;
  float4 ha, hb4, ia, ib;
  if (m < 12) {
    ha = *(const float4*)(sh + 8 * m); hb4 = *(const float4*)(sh + 8 * m + 4);
    ia = *(const float4*)(si + 8 * m); ib = *(const float4*)(si + 8 * m + 4);
  } else {  // k = 96..103 : 4 valid + 4 zero-pad
    ha = *(const float4*)(sh + 96); hb4 = make_float4(0.f, 0.f, 0.f, 0.f);
    ia = *(const float4*)(si + 96); ib = make_float4(0.f, 0.f, 0.f, 0.f);
  }
  uint4 uh, ui;
  uh.x = pk16(ha.x, ha.y); uh.y = pk16(ha.z, ha.w);
  uh.z = pk16(hb4.x, hb4.y); uh.w = pk16(hb4.z, hb4.w);
  ui.x = pk16(ia.x, ia.y); ui.y = pk16(ia.z, ia.w);
  ui.z = pk16(ib.x, ib.y); ui.w = pk16(ib.z, ib.w);
  whl[(size_t)b * NG + tid] = uh;
  wil[(size_t)b * NG + tid] = ui;
}

// ---- main: one block per layer. Whh f16 resident in LDS; recurrent step
// touches NO global memory (R6 falsified the byte-bound model; latency behind
// per-step barriers was the cost). Wih@x batched per chunk into named regs.
__launch_bounds__(512, 1)
__global__ void lstm_pipe_kernel(
    const float* __restrict__ input,   // [T, H] fp32
    const float* __restrict__ bih,     // [L, 4H]
    const float* __restrict__ bhh,     // [L, 4H]
    const float* __restrict__ Wout,    // [OUT, H]
    const float* __restrict__ bout,    // [OUT]
    float* __restrict__ out,           // [T, OUT]
    int* __restrict__ flags,           // [L-1, NC]
    unsigned short* __restrict__ xst,  // [L-1, T, KH] f16 inter-layer acts
    const uint4* __restrict__ whl,     // packed f16 Whh
    const uint4* __restrict__ wil)     // packed f16 Wih
{
  extern __shared__ __align__(16) char smem[];
  uint4* whlds = (uint4*)(smem + WH_OFF);
  unsigned short* xh = (unsigned short*)(smem + XH_OFF);
  unsigned short* och16 = (unsigned short*)(smem + OCH_OFF);
  unsigned short* hbs = (unsigned short*)(smem + HB_OFF);
  float* ochf = (float*)(smem + OCHF_OFF);

  const int l = blockIdx.x;
  const int tid = threadIdx.x;
  const int j = tid >> 2;
  const int g = tid & 3;
  const bool act = (tid < NG);
  const int row = act ? (g * HH + j) : 0;

  const uint4* wi0 = wil + (size_t)l * KC * NG + tid;  // stream per chunk
  const float bias = bih[l * NG + row] + bhh[l * NG + row];

  // ---- one-time: Whh f16 -> LDS [m][lane] (coalesced global, linear LDS) ----
  if (act) {
#pragma unroll
    for (int m = 0; m < KC; ++m)
      whlds[m * NG + tid] = whl[((size_t)l * KC + m) * NG + tid];
  }
  if (tid < KH) { hbs[tid] = 0; hbs[KH + tid] = 0; }  // h0 + pads
  if (tid < CC) {
    *(uint2*)(xh + tid * KH + HH) = make_uint2(0u, 0u);      // x pads
    *(uint2*)(och16 + tid * KH + HH) = make_uint2(0u, 0u);   // publish pads
  }
  float c = 0.f;
  __syncthreads();

  for (int ch = 0; ch < NC; ++ch) {
    // ---- acquire x chunk into LDS (f16) ----
    if (l == 0) {
      if (tid < 250) {
        float4 v = ((const float4*)(input + ch * CC * HH))[tid];
        int s = tid / 25, q = tid % 25;
        *(uint2*)(xh + s * KH + q * 4) = make_uint2(pk16(v.x, v.y), pk16(v.z, v.w));
      }
    } else {
      if (tid == 0) {
        const int* fl = flags + (l - 1) * NC + ch;
        while (__hip_atomic_load(fl, __ATOMIC_ACQUIRE, __HIP_MEMORY_SCOPE_AGENT) == 0)
          __builtin_amdgcn_s_sleep(1);
      }
      __syncthreads();
      const uint4* src =
          (const uint4*)(xst + ((size_t)(l - 1) * TT + (size_t)ch * CC) * KH);
      if (tid < 130) ((uint4*)xh)[tid] = src[tid];
    }
    __syncthreads();  // xh ready

    // ---- per-chunk batch: XGs = bias + Wih[row].x_s (named regs, no arrays) ----
    float XG0 = bias, XG1 = bias, XG2 = bias, XG3 = bias, XG4 = bias;
    float XG5 = bias, XG6 = bias, XG7 = bias, XG8 = bias, XG9 = bias;
    if (act) {
#define XGB(m, s)                                                   \
  {                                                                 \
    uint4 xv = ((const uint4*)(xh + (s)*KH))[m]; /* uniform bcast */\
    XG##s = fdot2u(vw.x, xv.x, XG##s);                              \
    XG##s = fdot2u(vw.y, xv.y, XG##s);                              \
    XG##s = fdot2u(vw.z, xv.z, XG##s);                              \
    XG##s = fdot2u(vw.w, xv.w, XG##s);                              \
  }
#define XGM(m)                                                      \
  {                                                                 \
    uint4 vw = wi0[(m)*NG]; /* one weight block live at a time */   \
    XGB(m, 0) XGB(m, 1) XGB(m, 2) XGB(m, 3) XGB(m, 4)               \
    XGB(m, 5) XGB(m, 6) XGB(m, 7) XGB(m, 8) XGB(m, 9)               \
  }
      XGM(0) XGM(1) XGM(2) XGM(3) XGM(4) XGM(5) XGM(6)
      XGM(7) XGM(8) XGM(9) XGM(10) XGM(11) XGM(12)
    }

    // ---- CC recurrent steps: pure LDS + VALU, one barrier each ----
#define DOT(m)                                                      \
  {                                                                 \
    uint4 hv = hb4[m];                 /* uniform broadcast */      \
    uint4 uw = whlds[(m)*NG + tid];    /* per-lane b128 */          \
    a0 = fdot2u(uw.x, hv.x, a0); a1 = fdot2u(uw.y, hv.y, a1);       \
    a2 = fdot2u(uw.z, hv.z, a2); a3 = fdot2u(uw.w, hv.w, a3);       \
  }
#define STEP(s, XGS)                                                \
  {                                                                 \
    __syncthreads(); /* hb[s&1] ready (xh/XG at s==0) */            \
    if (act) {                                                      \
      const uint4* hb4 = (const uint4*)(hbs + ((s)&1) * KH);        \
      float a0 = 0.f, a1 = 0.f, a2 = 0.f, a3 = 0.f;                 \
      DOT(0) DOT(1) DOT(2) DOT(3) DOT(4) DOT(5) DOT(6)              \
      DOT(7) DOT(8) DOT(9) DOT(10) DOT(11) DOT(12)                  \
      float aa = ((a0 + a1) + (a2 + a3)) + XGS;                     \
      bool isg = (g == 2);                                          \
      float mm = isg ? 2.f : 1.f;                                   \
      float sg = 1.f / (1.f + __expf(-mm * aa));                    \
      float vv = isg ? 2.f * sg - 1.f : sg;                         \
      float v1 = __shfl_xor(vv, 1);                                 \
      float v2v = __shfl_xor(vv, 2);                                \
      float v3 = __shfl_xor(v1, 2);                                 \
      if (g == 0) { /* vv=i v1=f v2v=g~ v3=o */                     \
        c = v1 * c + vv * v2v;                                      \
        float tc = 2.f / (1.f + __expf(-2.f * c)) - 1.f;            \
        float h = v3 * tc;                                          \
        hbs[(((s) + 1) & 1) * KH + j] =                             \
            __builtin_bit_cast(unsigned short, (_Float16)h);        \
        if (l < NL - 1)                                             \
          och16[(s)*KH + j] =                                       \
              __builtin_bit_cast(unsigned short, (_Float16)fmaxf(h, 0.f)); \
        else                                                        \
          ochf[(s)*HH + j] = h;                                     \
      }                                                             \
    }                                                               \
  }
    STEP(0, XG0) STEP(1, XG1) STEP(2, XG2) STEP(3, XG3) STEP(4, XG4)
    STEP(5, XG5) STEP(6, XG6) STEP(7, XG7) STEP(8, XG8) STEP(9, XG9)

    __syncthreads();  // last step's publish writes visible

    if (l < NL - 1) {
      // ---- publish chunk (f16): coalesced write + fence + flag ----
      uint4* dst = (uint4*)(xst + ((size_t)l * TT + (size_t)ch * CC) * KH);
      if (tid < 130) dst[tid] = ((const uint4*)och16)[tid];
      __syncthreads();  // all waves' global stores drained
      if (tid == 0) {
        __threadfence();
        __hip_atomic_store(flags + l * NC + ch, 1, __ATOMIC_RELEASE,
                           __HIP_MEMORY_SCOPE_AGENT);
      }
    } else {
      // ---- batched output projection for the chunk (fp32) ----
      if (tid < NG) {
        int p = tid >> 2, q = tid & 3;
        int s2 = p / 10, r = p % 10;
        const float* wrow = Wout + r * HH + q * 25;
        const float* hrow = ochf + s2 * HH + q * 25;
        float acc = 0.f;
#pragma unroll
        for (int m2 = 0; m2 < 25; ++m2) acc = fmaf(wrow[m2], hrow[m2], acc);
        acc += __shfl_xor(acc, 1);
        acc += __shfl_xor(acc, 2);
        if (q == 0) out[(ch * CC + s2) * NOUT + r] = sigm(acc + bout[r]);
      }
    }
  }
}

extern "C" void kernel_launch(void* const* d_in, const int* in_sizes, int n_in,
                              void* d_out, int out_size, void* d_ws, size_t ws_size,
                              hipStream_t stream) {
  const float* input = (const float*)d_in[0];
  const float* Wih   = (const float*)d_in[1];
  const float* Whh   = (const float*)d_in[2];
  const float* bih   = (const float*)d_in[3];
  const float* bhh   = (const float*)d_in[4];
  const float* Wout  = (const float*)d_in[5];
  const float* bout  = (const float*)d_in[6];
  float* out = (float*)d_out;

  // ws layout (bytes):
  //   [0, 2048)         flags ((L-1)*NC = 40 ints used)
  //   [2048, 85248)     xst16: (L-1)*T*KH halves = 83200
  //   [85248, 501248)   whl: 5*13*400 uint4 = 416000
  //   [501248, 917248)  wil: 5*13*400 uint4 = 416000
  int* flags = (int*)d_ws;
  unsigned short* xst = (unsigned short*)((char*)d_ws + 2048);
  uint4* whl = (uint4*)((char*)d_ws + 85248);
  uint4* wil = (uint4*)((char*)d_ws + 501248);

  // allow >64KB dynamic LDS (host-side, idempotent, capture-safe — proven R5)
  (void)hipFuncSetAttribute((const void*)lstm_pipe_kernel,
                            hipFuncAttributeMaxDynamicSharedMemorySize,
                            SMEM_BYTES);

  // flags must be zero at kernel start on EVERY call (graph replays included)
  hipMemsetAsync(d_ws, 0, 2048, stream);

  pack_w<<<dim3(NL * KC), dim3(512), 0, stream>>>(Wih, Whh, wil, whl);

  lstm_pipe_kernel<<<dim3(NL), dim3(512), SMEM_BYTES, stream>>>(
      input, bih, bhh, Wout, bout, out, flags, xst, whl, wil);
}

// Round 8
// 187.200 us; speedup vs baseline: 7.0207x; 1.1746x over previous
//
#include <hip/hip_runtime.h>

#define TT 100
#define HH 100
#define NL 5
#define NOUT 10
#define NG 400        // 4*H gate rows
#define CC 10         // timesteps per inter-layer handoff chunk
#define NC (TT / CC)  // chunks
#define KC 13         // k-chunks of 8 halves (104 halves, last 4 zero-pad)
#define KH 104        // padded k length in halves

typedef _Float16 h2f __attribute__((ext_vector_type(2)));

__device__ __forceinline__ float sigm(float x) { return 1.f / (1.f + __expf(-x)); }

__device__ __forceinline__ float fdot2u(unsigned a, unsigned b, float c) {
#if __has_builtin(__builtin_amdgcn_fdot2)
  return __builtin_amdgcn_fdot2(__builtin_bit_cast(h2f, a),
                                __builtin_bit_cast(h2f, b), c, false);
#else
  float d;
  asm("v_dot2_f32_f16 %0, %1, %2, %3" : "=v"(d) : "v"(a), "v"(b), "v"(c));
  return d;
#endif
}

__device__ __forceinline__ unsigned pk16(float lo, float hi) {
  _Float16 l = (_Float16)lo, h = (_Float16)hi;
  return (unsigned)__builtin_bit_cast(unsigned short, l) |
         ((unsigned)__builtin_bit_cast(unsigned short, h) << 16);
}

#define R13(M) M(0) M(1) M(2) M(3) M(4) M(5) M(6) M(7) M(8) M(9) M(10) M(11) M(12)

// AGPR write/read: allocator-proof register residency (R3/R4/R5: plain named
// vars always spilled; AGPR file has no other users in this MFMA-free kernel).
#define AWR(D, S) asm volatile("v_accvgpr_write_b32 %0, %1" : "=a"(D) : "v"(S));
#define ARD(D, S) asm volatile("v_accvgpr_read_b32 %0, %1" : "=v"(D) : "a"(S));

// One block per layer, wavefront-pipelined over timestep chunks (CC=10).
// Weights live in AGPRs: 52 uint (f16x2 Whh row) + 52 uint (Wih row) per lane.
// Recurrent step: 13 uniform LDS h-broadcasts + 52 agpr reads + 52 v_dot2.
__global__ __attribute__((amdgpu_flat_work_group_size(512, 512),
                          amdgpu_waves_per_eu(2, 2)))
void lstm_pipe_kernel(
    const float* __restrict__ input,   // [T, H] fp32
    const float* __restrict__ Wih,     // [L, 4H, H]
    const float* __restrict__ Whh,     // [L, 4H, H]
    const float* __restrict__ bih,     // [L, 4H]
    const float* __restrict__ bhh,     // [L, 4H]
    const float* __restrict__ Wout,    // [OUT, H]
    const float* __restrict__ bout,    // [OUT]
    float* __restrict__ out,           // [T, OUT]
    int* __restrict__ flags,           // [L-1, NC]
    unsigned short* __restrict__ xst)  // [L-1, T, KH] f16 inter-layer acts
{
  __shared__ __align__(16) unsigned short xh[CC * KH];     // x chunk, f16
  __shared__ __align__(16) unsigned short och16[CC * KH];  // publish chunk, f16
  __shared__ __align__(16) unsigned short hbs[2 * KH];     // h dbuf, f16
  __shared__ __align__(16) float ochf[CC * HH];            // layer-4 h, fp32

  const int l = blockIdx.x;
  const int tid = threadIdx.x;
  const int j = tid >> 2;
  const int g = tid & 3;
  const bool act = (tid < NG);
  const int row = act ? (g * HH + j) : 0;

  // ---- 104 AGPR weight slots per lane ----
#define DECL4(P, m) unsigned P##m##_0, P##m##_1, P##m##_2, P##m##_3;
#define DWH(m) DECL4(WH, m)
#define DWI(m) DECL4(WI, m)
  R13(DWH) R13(DWI)

  if (act) {
    const float* hr = Whh + ((size_t)l * NG + row) * HH;
    const float* ir = Wih + ((size_t)l * NG + row) * HH;
#define LW(P, src, m)                                                        \
  {                                                                          \
    float4 fa = *(const float4*)((src) + 8 * (m));                           \
    float4 fb = ((m) < 12) ? *(const float4*)((src) + 8 * (m) + 4)           \
                           : make_float4(0.f, 0.f, 0.f, 0.f);                \
    AWR(P##m##_0, pk16(fa.x, fa.y)) AWR(P##m##_1, pk16(fa.z, fa.w))          \
    AWR(P##m##_2, pk16(fb.x, fb.y)) AWR(P##m##_3, pk16(fb.z, fb.w))          \
  }
#define LWH(m) LW(WH, hr, m)
#define LWI(m) LW(WI, ir, m)
    R13(LWH) R13(LWI)
  }
  const float bias = bih[l * NG + row] + bhh[l * NG + row];

  // one-time zero: h0 + k-pads (pads never overwritten afterwards)
  if (tid < KH) { hbs[tid] = 0; hbs[KH + tid] = 0; }
  if (tid < CC) {
    *(uint2*)(xh + tid * KH + HH) = make_uint2(0u, 0u);
    *(uint2*)(och16 + tid * KH + HH) = make_uint2(0u, 0u);
  }
  float c = 0.f;
  __syncthreads();

  for (int ch = 0; ch < NC; ++ch) {
    // ---- acquire x chunk into LDS (f16) ----
    if (l == 0) {
      if (tid < 250) {
        float4 v = ((const float4*)(input + ch * CC * HH))[tid];
        int s = tid / 25, q = tid % 25;
        *(uint2*)(xh + s * KH + q * 4) = make_uint2(pk16(v.x, v.y), pk16(v.z, v.w));
      }
    } else {
      if (tid == 0) {
        const int* fl = flags + (l - 1) * NC + ch;
        while (__hip_atomic_load(fl, __ATOMIC_ACQUIRE, __HIP_MEMORY_SCOPE_AGENT) == 0)
          __builtin_amdgcn_s_sleep(1);
      }
      __syncthreads();
      const uint4* src =
          (const uint4*)(xst + ((size_t)(l - 1) * TT + (size_t)ch * CC) * KH);
      if (tid < 130) ((uint4*)xh)[tid] = src[tid];
    }
    __syncthreads();  // xh ready

    // ---- per-chunk batch: XGs = bias + Wih[row].x_s (AGPR weights) ----
    float XG0 = bias, XG1 = bias, XG2 = bias, XG3 = bias, XG4 = bias;
    float XG5 = bias, XG6 = bias, XG7 = bias, XG8 = bias, XG9 = bias;
    if (act) {
#define XGB(m, s)                                                    \
  {                                                                  \
    uint4 xv = ((const uint4*)(xh + (s)*KH))[m]; /* uniform bcast */ \
    XG##s = fdot2u(u0, xv.x, XG##s);                                 \
    XG##s = fdot2u(u1, xv.y, XG##s);                                 \
    XG##s = fdot2u(u2, xv.z, XG##s);                                 \
    XG##s = fdot2u(u3, xv.w, XG##s);                                 \
  }
#define XGM(m)                                                       \
  {                                                                  \
    unsigned u0, u1, u2, u3;                                         \
    ARD(u0, WI##m##_0) ARD(u1, WI##m##_1)                            \
    ARD(u2, WI##m##_2) ARD(u3, WI##m##_3)                            \
    XGB(m, 0) XGB(m, 1) XGB(m, 2) XGB(m, 3) XGB(m, 4)                \
    XGB(m, 5) XGB(m, 6) XGB(m, 7) XGB(m, 8) XGB(m, 9)                \
  }
      XGM(0) XGM(1) XGM(2) XGM(3) XGM(4) XGM(5) XGM(6)
      XGM(7) XGM(8) XGM(9) XGM(10) XGM(11) XGM(12)
    }

    // ---- CC recurrent steps: AGPR weights + uniform LDS h, 1 barrier each ----
#define DOT(m)                                                       \
  {                                                                  \
    unsigned u0, u1, u2, u3;                                         \
    ARD(u0, WH##m##_0) ARD(u1, WH##m##_1)                            \
    ARD(u2, WH##m##_2) ARD(u3, WH##m##_3)                            \
    uint4 hv = hb4[m]; /* uniform broadcast */                       \
    a0 = fdot2u(u0, hv.x, a0); a1 = fdot2u(u1, hv.y, a1);            \
    a2 = fdot2u(u2, hv.z, a2); a3 = fdot2u(u3, hv.w, a3);            \
  }
#define STEP(s, XGS)                                                 \
  {                                                                  \
    __syncthreads(); /* hbs[s&1] ready (xh/XG at s==0) */            \
    if (act) {                                                       \
      const uint4* hb4 = (const uint4*)(hbs + ((s)&1) * KH);         \
      float a0 = 0.f, a1 = 0.f, a2 = 0.f, a3 = 0.f;                  \
      DOT(0) DOT(1) DOT(2) DOT(3) DOT(4) DOT(5) DOT(6)               \
      DOT(7) DOT(8) DOT(9) DOT(10) DOT(11) DOT(12)                   \
      float aa = ((a0 + a1) + (a2 + a3)) + XGS;                      \
      bool isg = (g == 2);                                           \
      float mm = isg ? 2.f : 1.f;                                    \
      float sg = 1.f / (1.f + __expf(-mm * aa));                     \
      float vv = isg ? 2.f * sg - 1.f : sg;                          \
      float v1 = __shfl_xor(vv, 1);                                  \
      float v2v = __shfl_xor(vv, 2);                                 \
      float v3 = __shfl_xor(v1, 2);                                  \
      if (g == 0) { /* vv=i v1=f v2v=g~ v3=o */                      \
        c = v1 * c + vv * v2v;                                       \
        float tc = 2.f / (1.f + __expf(-2.f * c)) - 1.f;             \
        float h = v3 * tc;                                           \
        hbs[(((s) + 1) & 1) * KH + j] =                              \
            __builtin_bit_cast(unsigned short, (_Float16)h);         \
        if (l < NL - 1)                                              \
          och16[(s)*KH + j] =                                        \
              __builtin_bit_cast(unsigned short, (_Float16)fmaxf(h, 0.f)); \
        else                                                         \
          ochf[(s)*HH + j] = h;                                      \
      }                                                              \
    }                                                                \
  }
    STEP(0, XG0) STEP(1, XG1) STEP(2, XG2) STEP(3, XG3) STEP(4, XG4)
    STEP(5, XG5) STEP(6, XG6) STEP(7, XG7) STEP(8, XG8) STEP(9, XG9)

    __syncthreads();  // last step's publish writes visible

    if (l < NL - 1) {
      // ---- publish chunk (f16): coalesced write + fence + flag ----
      uint4* dst = (uint4*)(xst + ((size_t)l * TT + (size_t)ch * CC) * KH);
      if (tid < 130) dst[tid] = ((const uint4*)och16)[tid];
      __syncthreads();  // all waves' global stores drained
      if (tid == 0) {
        __threadfence();
        __hip_atomic_store(flags + l * NC + ch, 1, __ATOMIC_RELEASE,
                           __HIP_MEMORY_SCOPE_AGENT);
      }
    } else {
      // ---- batched output projection for the chunk (fp32) ----
      if (tid < NG) {
        int p = tid >> 2, q = tid & 3;
        int s2 = p / 10, r = p % 10;
        const float* wrow = Wout + r * HH + q * 25;
        const float* hrow = ochf + s2 * HH + q * 25;
        float acc = 0.f;
#pragma unroll
        for (int m2 = 0; m2 < 25; ++m2) acc = fmaf(wrow[m2], hrow[m2], acc);
        acc += __shfl_xor(acc, 1);
        acc += __shfl_xor(acc, 2);
        if (q == 0) out[(ch * CC + s2) * NOUT + r] = sigm(acc + bout[r]);
      }
    }
  }
}

extern "C" void kernel_launch(void* const* d_in, const int* in_sizes, int n_in,
                              void* d_out, int out_size, void* d_ws, size_t ws_size,
                              hipStream_t stream) {
  const float* input = (const float*)d_in[0];
  const float* Wih   = (const float*)d_in[1];
  const float* Whh   = (const float*)d_in[2];
  const float* bih   = (const float*)d_in[3];
  const float* bhh   = (const float*)d_in[4];
  const float* Wout  = (const float*)d_in[5];
  const float* bout  = (const float*)d_in[6];
  float* out = (float*)d_out;

  // ws layout (bytes):
  //   [0, 2048)       flags ((L-1)*NC = 40 ints used)
  //   [2048, 85248)   xst16: (L-1)*T*KH halves = 83200
  int* flags = (int*)d_ws;
  unsigned short* xst = (unsigned short*)((char*)d_ws + 2048);

  // flags must be zero at kernel start on EVERY call (graph replays included)
  hipMemsetAsync(d_ws, 0, 2048, stream);

  lstm_pipe_kernel<<<dim3(NL), dim3(512), 0, stream>>>(
      input, Wih, Whh, bih, bhh, Wout, bout, out, flags, xst);
}